// Round 1
// baseline (173.023 us; speedup 1.0000x reference)
//
#include <hip/hip_runtime.h>
#include <hip/hip_bf16.h>
#include <cstdint>

#define NPOS 512
#define NNEG 512
#define BATCH 8
#define DDIM 128
#define NLEM 32768

typedef __attribute__((ext_vector_type(4))) float f32x4;
typedef __attribute__((ext_vector_type(16))) float f32x16;
typedef __attribute__((ext_vector_type(8))) short short8;

__device__ __forceinline__ unsigned short f2bf(float f) {
  unsigned u = __float_as_uint(f);
  u = (u + 0x7FFFu + ((u >> 16) & 1u)) >> 16;
  return (unsigned short)u;
}

// C[r, n] = sum_d A[r, d] * Bm[n, d]   (NT GEMM, K = 128, bf16 MFMA)
// A row r maps to x row ((r>>9)<<10) + (r&511) + a_off   (pos: a_off=0, neg: a_off=512)
__global__ __launch_bounds__(256) void gemm_kernel(
    const float* __restrict__ X, const float* __restrict__ Bm,
    float* __restrict__ C, int ldc, int a_off) {
  __shared__ short lds[2 * 128 * 128];  // 64 KB: A tile then B tile (bf16)
  short* ldsA = lds;
  short* ldsB = lds + 128 * 128;

  const int t = threadIdx.x;
  const int m0 = blockIdx.x * 128;
  const int n0 = blockIdx.y * 128;

  // ---- stage: global f32 -> bf16 -> LDS (XOR-swizzled 16B slots) ----
  const int slot = t & 15;   // which 8-element (16B) slot in the 128-wide row
  const int rsub = t >> 4;   // 0..15

#pragma unroll
  for (int it = 0; it < 8; ++it) {
    const int row = it * 16 + rsub;  // 0..127
    // A tile
    const int gr = m0 + row;
    const int xrow = ((gr >> 9) << 10) + (gr & 511) + a_off;
    const f32x4* pa = (const f32x4*)(X + (size_t)xrow * DDIM + slot * 8);
    const f32x4 a0 = pa[0], a1 = pa[1];
    // B tile (memory rows)
    const f32x4* pb = (const f32x4*)(Bm + (size_t)(n0 + row) * DDIM + slot * 8);
    const f32x4 b0 = pb[0], b1 = pb[1];

    short8 wa, wb;
    wa[0] = (short)f2bf(a0[0]); wa[1] = (short)f2bf(a0[1]);
    wa[2] = (short)f2bf(a0[2]); wa[3] = (short)f2bf(a0[3]);
    wa[4] = (short)f2bf(a1[0]); wa[5] = (short)f2bf(a1[1]);
    wa[6] = (short)f2bf(a1[2]); wa[7] = (short)f2bf(a1[3]);
    wb[0] = (short)f2bf(b0[0]); wb[1] = (short)f2bf(b0[1]);
    wb[2] = (short)f2bf(b0[2]); wb[3] = (short)f2bf(b0[3]);
    wb[4] = (short)f2bf(b1[0]); wb[5] = (short)f2bf(b1[1]);
    wb[6] = (short)f2bf(b1[2]); wb[7] = (short)f2bf(b1[3]);

    const int ss = (slot ^ (row & 15)) * 8;  // swizzled slot, in shorts
    *(short8*)&ldsA[row * 128 + ss] = wa;
    *(short8*)&ldsB[row * 128 + ss] = wb;
  }
  __syncthreads();

  // ---- compute: 4 waves, each owns a 64x64 sub-tile (2x2 frags of 32x32) ----
  const int lane = t & 63;
  const int wv = t >> 6;
  const int wr = wv >> 1, wc = wv & 1;
  const int la = lane & 31, lb = lane >> 5;

  f32x16 acc[2][2] = {};

#pragma unroll
  for (int kk = 0; kk < 8; ++kk) {  // K = 8 * 16
    short8 af[2], bfr[2];
#pragma unroll
    for (int m2 = 0; m2 < 2; ++m2) {
      const int row = wr * 64 + m2 * 32 + la;
      const int ss = ((kk * 2 + lb) ^ (row & 15)) * 8;
      af[m2] = *(const short8*)&ldsA[row * 128 + ss];
    }
#pragma unroll
    for (int n2 = 0; n2 < 2; ++n2) {
      const int row = wc * 64 + n2 * 32 + la;
      const int ss = ((kk * 2 + lb) ^ (row & 15)) * 8;
      bfr[n2] = *(const short8*)&ldsB[row * 128 + ss];
    }
#pragma unroll
    for (int m2 = 0; m2 < 2; ++m2)
#pragma unroll
      for (int n2 = 0; n2 < 2; ++n2)
        acc[m2][n2] = __builtin_amdgcn_mfma_f32_32x32x16_bf16(
            af[m2], bfr[n2], acc[m2][n2], 0, 0, 0);
  }

  // ---- epilogue: C/D layout 32x32: col = lane&31, row = (r&3) + 8*(r>>2) + 4*(lane>>5)
#pragma unroll
  for (int m2 = 0; m2 < 2; ++m2) {
#pragma unroll
    for (int n2 = 0; n2 < 2; ++n2) {
      const int col = n0 + wc * 64 + n2 * 32 + la;
      const int rbase = m0 + wr * 64 + m2 * 32 + lb * 4;
#pragma unroll
      for (int r = 0; r < 16; ++r) {
        const int row = rbase + (r & 3) + 8 * (r >> 2);
        C[(size_t)row * ldc + col] = acc[m2][n2][r];
      }
    }
  }
}

__global__ void y_kernel(const int* __restrict__ y, float* __restrict__ out) {
  const int i = blockIdx.x * blockDim.x + threadIdx.x;
  if (i < BATCH * NPOS) out[i] = (float)y[i];
}

// One wave per memory row; exact f32 math; L2-normalize each row.
__global__ __launch_bounds__(256) void newmem_kernel(
    const float* __restrict__ X, const int* __restrict__ vis,
    const float* __restrict__ Mem, const int* __restrict__ lru_p,
    float* __restrict__ out) {
  const int wv = threadIdx.x >> 6;
  const int lane = threadIdx.x & 63;
  const int r = blockIdx.x * 4 + wv;
  const int start = NPOS + lru_p[0] * (NNEG * BATCH);

  const int d0 = lane, d1 = lane + 64;
  float v0, v1;

  if (r < NPOS) {
    const float s0 = Mem[(size_t)r * DDIM + d0];
    const float s1 = Mem[(size_t)r * DDIM + d1];
    float a0 = 0.f, a1 = 0.f;
#pragma unroll
    for (int b = 0; b < BATCH; ++b) {
      const float w = (float)vis[b * NPOS + r];
      const float* px = X + (size_t)(b * (NPOS + NNEG) + r) * DDIM;
      a0 += w * px[d0];
      a1 += w * px[d1];
    }
    v0 = 0.5f * s0 + 0.0625f * a0;  // 0.5*mem + 0.5*mean_b(vis*x)
    v1 = 0.5f * s1 + 0.0625f * a1;
  } else if (r >= start && r < start + BATCH * NNEG) {
    const int q = r - start;
    const int b = q >> 9, n = q & 511;
    const float* px = X + (size_t)(b * (NPOS + NNEG) + NPOS + n) * DDIM;
    v0 = px[d0];
    v1 = px[d1];
  } else {
    v0 = Mem[(size_t)r * DDIM + d0];
    v1 = Mem[(size_t)r * DDIM + d1];
  }

  float s = v0 * v0 + v1 * v1;
#pragma unroll
  for (int off = 32; off; off >>= 1) s += __shfl_xor(s, off, 64);
  const float inv = 1.0f / fmaxf(sqrtf(s), 1e-12f);
  out[(size_t)r * DDIM + d0] = v0 * inv;
  out[(size_t)r * DDIM + d1] = v1 * inv;
}

extern "C" void kernel_launch(void* const* d_in, const int* in_sizes, int n_in,
                              void* d_out, int out_size, void* d_ws, size_t ws_size,
                              hipStream_t stream) {
  const float* x = (const float*)d_in[0];
  const int* y = (const int*)d_in[1];
  const int* visible = (const int*)d_in[2];
  const float* memory = (const float*)d_in[3];
  const int* lru = (const int*)d_in[4];
  float* out = (float*)d_out;

  const size_t OFF_Y = (size_t)BATCH * NPOS * NLEM;          // 134217728
  const size_t OFF_NOISE = OFF_Y + (size_t)BATCH * NPOS;     // +4096
  const size_t OFF_MEM = OFF_NOISE + (size_t)BATCH * NNEG * NPOS;  // +2097152

  // similarity: (4096 x 32768), A = x[:, :512, :], B = memory
  gemm_kernel<<<dim3(32, 256), 256, 0, stream>>>(x, memory, out, NLEM, 0);
  // noise_similarity: (4096 x 512), A = x[:, 512:, :], B = memory[:512]
  gemm_kernel<<<dim3(32, 4), 256, 0, stream>>>(x, memory, out + OFF_NOISE, NPOS, NPOS);
  // y_idx
  y_kernel<<<16, 256, 0, stream>>>(y, out + OFF_Y);
  // new_mem
  newmem_kernel<<<NLEM / 4, 256, 0, stream>>>(x, visible, memory, lru, out + OFF_MEM);
}

// Round 2
// 130.399 us; speedup vs baseline: 1.3269x; 1.3269x over previous
//
#include <hip/hip_runtime.h>
#include <hip/hip_bf16.h>
#include <cstdint>

#define NPOS 512
#define NNEG 512
#define BATCH 8
#define DDIM 128
#define NLEM 32768
#define NX_ELEM (BATCH * (NPOS + NNEG) * DDIM)  // 1048576
#define NM_ELEM (NLEM * DDIM)                   // 4194304

typedef __attribute__((ext_vector_type(4))) float f32x4;
typedef __attribute__((ext_vector_type(16))) float f32x16;
typedef __attribute__((ext_vector_type(8))) short short8;

__device__ __forceinline__ unsigned short f2bf(float f) {
  unsigned u = __float_as_uint(f);
  u = (u + 0x7FFFu + ((u >> 16) & 1u)) >> 16;
  return (unsigned short)u;
}

__device__ __forceinline__ short8 cvt8(f32x4 a0, f32x4 a1) {
  short8 w;
  w[0] = (short)f2bf(a0[0]); w[1] = (short)f2bf(a0[1]);
  w[2] = (short)f2bf(a0[2]); w[3] = (short)f2bf(a0[3]);
  w[4] = (short)f2bf(a1[0]); w[5] = (short)f2bf(a1[1]);
  w[6] = (short)f2bf(a1[2]); w[7] = (short)f2bf(a1[3]);
  return w;
}

// async 16B global -> LDS (linear dest: wave-uniform base + lane*16)
__device__ __forceinline__ void async16(const void* g, void* l) {
  __builtin_amdgcn_global_load_lds(
      (const __attribute__((address_space(1))) unsigned int*)g,
      (__attribute__((address_space(3))) unsigned int*)l, 16, 0, 0);
}

// ---- shared newmem row logic (one wave per row, exact f32) ----
__device__ __forceinline__ void newmem_row(int r, int lane, const float* __restrict__ X,
                                           const int* __restrict__ vis,
                                           const float* __restrict__ Mem, int start,
                                           float* __restrict__ out) {
  const int d0 = lane, d1 = lane + 64;
  float v0, v1;
  if (r < NPOS) {
    const float s0 = Mem[(size_t)r * DDIM + d0];
    const float s1 = Mem[(size_t)r * DDIM + d1];
    float a0 = 0.f, a1 = 0.f;
#pragma unroll
    for (int b = 0; b < BATCH; ++b) {
      const float w = (float)vis[b * NPOS + r];
      const float* px = X + (size_t)(b * (NPOS + NNEG) + r) * DDIM;
      a0 += w * px[d0];
      a1 += w * px[d1];
    }
    v0 = 0.5f * s0 + 0.0625f * a0;
    v1 = 0.5f * s1 + 0.0625f * a1;
  } else if (r >= start && r < start + BATCH * NNEG) {
    const int q = r - start;
    const int b = q >> 9, n = q & 511;
    const float* px = X + (size_t)(b * (NPOS + NNEG) + NPOS + n) * DDIM;
    v0 = px[d0];
    v1 = px[d1];
  } else {
    v0 = Mem[(size_t)r * DDIM + d0];
    v1 = Mem[(size_t)r * DDIM + d1];
  }
  float s = v0 * v0 + v1 * v1;
#pragma unroll
  for (int off = 32; off; off >>= 1) s += __shfl_xor(s, off, 64);
  const float inv = 1.0f / fmaxf(sqrtf(s), 1e-12f);
  out[(size_t)r * DDIM + d0] = v0 * inv;
  out[(size_t)r * DDIM + d1] = v1 * inv;
}

// ==== prep: convert x+memory to bf16 in ws, write y_idx, write new_mem ====
// blocks: [0,512) x-convert | [512,2560) mem-convert | [2560,2576) y | [2576,10768) newmem
__global__ __launch_bounds__(256) void prep_kernel(
    const float* __restrict__ X, const int* __restrict__ y,
    const int* __restrict__ vis, const float* __restrict__ Mem,
    const int* __restrict__ lru_p, unsigned short* __restrict__ xb,
    unsigned short* __restrict__ mb, float* __restrict__ out_y,
    float* __restrict__ out_mem) {
  const int blk = blockIdx.x;
  if (blk < 512) {
    const size_t i = ((size_t)blk * 256 + threadIdx.x) * 8;
    *(short8*)(xb + i) = cvt8(*(const f32x4*)(X + i), *(const f32x4*)(X + i + 4));
  } else if (blk < 2560) {
    const size_t i = ((size_t)(blk - 512) * 256 + threadIdx.x) * 8;
    *(short8*)(mb + i) = cvt8(*(const f32x4*)(Mem + i), *(const f32x4*)(Mem + i + 4));
  } else if (blk < 2576) {
    const int i = (blk - 2560) * 256 + threadIdx.x;
    out_y[i] = (float)y[i];
  } else {
    const int r = (blk - 2576) * 4 + (threadIdx.x >> 6);
    const int start = NPOS + lru_p[0] * (NNEG * BATCH);
    newmem_row(r, threadIdx.x & 63, X, vis, Mem, start, out_mem);
  }
}

// ==== fast GEMM: bf16 inputs staged via global_load_lds ====
// by < 256: similarity (A = x pos rows, B = all memory, ldc = NLEM)
// by >= 256: noise     (A = x neg rows, B = memory[:512], ldc = NPOS)
__global__ __launch_bounds__(256) void gemm_bf16_kernel(
    const unsigned short* __restrict__ Xb, const unsigned short* __restrict__ Mb,
    float* __restrict__ Csim, float* __restrict__ Cnoise) {
  __shared__ short lds[2 * 128 * 128];  // 64 KB: A then B
  short* ldsA = lds;
  short* ldsB = lds + 128 * 128;

  const int bx = blockIdx.x, by = blockIdx.y;
  const int m0 = bx * 128;
  int n0, a_off, ldc;
  float* C;
  if (by < 256) { n0 = by * 128; a_off = 0;    C = Csim;   ldc = NLEM; }
  else          { n0 = (by - 256) * 128; a_off = NPOS; C = Cnoise; ldc = NPOS; }
  // 128 consecutive A rows in xb (tile never crosses a batch boundary)
  const int xbase = ((m0 >> 9) << 10) + (m0 & 511) + a_off;

  const int t = threadIdx.x;
  const int lane = t & 63;
  const int wv = t >> 6;

  // ---- stage: linear LDS dest, inverse-XOR-swizzled global source ----
  {
    const int rl = lane >> 4;      // row within 4-row group
    const int slot = lane & 15;    // 16B slot this lane fills
#pragma unroll
    for (int i = 0; i < 8; ++i) {
      const int rowb = wv * 32 + i * 4;       // wave-uniform base row
      const int row = rowb + rl;              // this lane's row
      const int ss = slot ^ (row & 15);       // source slot (involution)
      async16(Xb + (size_t)(xbase + row) * DDIM + ss * 8, &ldsA[rowb * 128]);
      async16(Mb + (size_t)(n0 + row) * DDIM + ss * 8, &ldsB[rowb * 128]);
    }
  }
  __syncthreads();  // drains vmcnt(0) -> all LDS data ready

  // ---- compute: 4 waves x 2x2 frags of 32x32x16 ----
  const int wr = wv >> 1, wc = wv & 1;
  const int la = lane & 31, lb = lane >> 5;

  f32x16 acc[2][2] = {};
#pragma unroll
  for (int kk = 0; kk < 8; ++kk) {
    short8 af[2], bfr[2];
#pragma unroll
    for (int m2 = 0; m2 < 2; ++m2) {
      const int row = wr * 64 + m2 * 32 + la;
      const int ss = ((kk * 2 + lb) ^ (row & 15)) * 8;
      af[m2] = *(const short8*)&ldsA[row * 128 + ss];
    }
#pragma unroll
    for (int n2 = 0; n2 < 2; ++n2) {
      const int row = wc * 64 + n2 * 32 + la;
      const int ss = ((kk * 2 + lb) ^ (row & 15)) * 8;
      bfr[n2] = *(const short8*)&ldsB[row * 128 + ss];
    }
#pragma unroll
    for (int m2 = 0; m2 < 2; ++m2)
#pragma unroll
      for (int n2 = 0; n2 < 2; ++n2)
        acc[m2][n2] = __builtin_amdgcn_mfma_f32_32x32x16_bf16(
            af[m2], bfr[n2], acc[m2][n2], 0, 0, 0);
  }

  // ---- epilogue: 32x32 C/D layout: col=lane&31, row=(r&3)+8*(r>>2)+4*(lane>>5)
#pragma unroll
  for (int m2 = 0; m2 < 2; ++m2) {
#pragma unroll
    for (int n2 = 0; n2 < 2; ++n2) {
      const int col = n0 + wc * 64 + n2 * 32 + la;
      const int rbase = m0 + wr * 64 + m2 * 32 + lb * 4;
#pragma unroll
      for (int r = 0; r < 16; ++r) {
        const int row = rbase + (r & 3) + 8 * (r >> 2);
        C[(size_t)row * ldc + col] = acc[m2][n2][r];
      }
    }
  }
}

// ================= fallback path (round-1 kernels, used if ws too small) ====
__global__ __launch_bounds__(256) void gemm_conv_kernel(
    const float* __restrict__ X, const float* __restrict__ Bm,
    float* __restrict__ C, int ldc, int a_off) {
  __shared__ short lds[2 * 128 * 128];
  short* ldsA = lds;
  short* ldsB = lds + 128 * 128;
  const int t = threadIdx.x;
  const int m0 = blockIdx.x * 128;
  const int n0 = blockIdx.y * 128;
  const int slot = t & 15;
  const int rsub = t >> 4;
#pragma unroll
  for (int it = 0; it < 8; ++it) {
    const int row = it * 16 + rsub;
    const int gr = m0 + row;
    const int xrow = ((gr >> 9) << 10) + (gr & 511) + a_off;
    const f32x4* pa = (const f32x4*)(X + (size_t)xrow * DDIM + slot * 8);
    const f32x4* pb = (const f32x4*)(Bm + (size_t)(n0 + row) * DDIM + slot * 8);
    short8 wa = cvt8(pa[0], pa[1]);
    short8 wb = cvt8(pb[0], pb[1]);
    const int ss = (slot ^ (row & 15)) * 8;
    *(short8*)&ldsA[row * 128 + ss] = wa;
    *(short8*)&ldsB[row * 128 + ss] = wb;
  }
  __syncthreads();
  const int lane = t & 63;
  const int wv = t >> 6;
  const int wr = wv >> 1, wc = wv & 1;
  const int la = lane & 31, lb = lane >> 5;
  f32x16 acc[2][2] = {};
#pragma unroll
  for (int kk = 0; kk < 8; ++kk) {
    short8 af[2], bfr[2];
#pragma unroll
    for (int m2 = 0; m2 < 2; ++m2) {
      const int row = wr * 64 + m2 * 32 + la;
      const int ss = ((kk * 2 + lb) ^ (row & 15)) * 8;
      af[m2] = *(const short8*)&ldsA[row * 128 + ss];
    }
#pragma unroll
    for (int n2 = 0; n2 < 2; ++n2) {
      const int row = wc * 64 + n2 * 32 + la;
      const int ss = ((kk * 2 + lb) ^ (row & 15)) * 8;
      bfr[n2] = *(const short8*)&ldsB[row * 128 + ss];
    }
#pragma unroll
    for (int m2 = 0; m2 < 2; ++m2)
#pragma unroll
      for (int n2 = 0; n2 < 2; ++n2)
        acc[m2][n2] = __builtin_amdgcn_mfma_f32_32x32x16_bf16(
            af[m2], bfr[n2], acc[m2][n2], 0, 0, 0);
  }
#pragma unroll
  for (int m2 = 0; m2 < 2; ++m2)
#pragma unroll
    for (int n2 = 0; n2 < 2; ++n2) {
      const int col = n0 + wc * 64 + n2 * 32 + la;
      const int rbase = m0 + wr * 64 + m2 * 32 + lb * 4;
#pragma unroll
      for (int r = 0; r < 16; ++r) {
        const int row = rbase + (r & 3) + 8 * (r >> 2);
        C[(size_t)row * ldc + col] = acc[m2][n2][r];
      }
    }
}

__global__ void y_kernel(const int* __restrict__ y, float* __restrict__ out) {
  const int i = blockIdx.x * blockDim.x + threadIdx.x;
  if (i < BATCH * NPOS) out[i] = (float)y[i];
}

__global__ __launch_bounds__(256) void newmem_kernel(
    const float* __restrict__ X, const int* __restrict__ vis,
    const float* __restrict__ Mem, const int* __restrict__ lru_p,
    float* __restrict__ out) {
  const int r = blockIdx.x * 4 + (threadIdx.x >> 6);
  const int start = NPOS + lru_p[0] * (NNEG * BATCH);
  newmem_row(r, threadIdx.x & 63, X, vis, Mem, start, out);
}

extern "C" void kernel_launch(void* const* d_in, const int* in_sizes, int n_in,
                              void* d_out, int out_size, void* d_ws, size_t ws_size,
                              hipStream_t stream) {
  const float* x = (const float*)d_in[0];
  const int* y = (const int*)d_in[1];
  const int* visible = (const int*)d_in[2];
  const float* memory = (const float*)d_in[3];
  const int* lru = (const int*)d_in[4];
  float* out = (float*)d_out;

  const size_t OFF_Y = (size_t)BATCH * NPOS * NLEM;
  const size_t OFF_NOISE = OFF_Y + (size_t)BATCH * NPOS;
  const size_t OFF_MEM = OFF_NOISE + (size_t)BATCH * NNEG * NPOS;

  const size_t need = (size_t)(NX_ELEM + NM_ELEM) * 2;  // 10.5 MB of bf16 scratch
  if (ws_size >= need) {
    unsigned short* xb = (unsigned short*)d_ws;
    unsigned short* mb = xb + NX_ELEM;
    prep_kernel<<<2576 + NLEM / 4, 256, 0, stream>>>(
        x, y, visible, memory, lru, xb, mb, out + OFF_Y, out + OFF_MEM);
    gemm_bf16_kernel<<<dim3(32, 260), 256, 0, stream>>>(
        xb, mb, out, out + OFF_NOISE);
  } else {
    gemm_conv_kernel<<<dim3(32, 256), 256, 0, stream>>>(x, memory, out, NLEM, 0);
    gemm_conv_kernel<<<dim3(32, 4), 256, 0, stream>>>(x, memory, out + OFF_NOISE, NPOS, NPOS);
    y_kernel<<<16, 256, 0, stream>>>(y, out + OFF_Y);
    newmem_kernel<<<NLEM / 4, 256, 0, stream>>>(x, visible, memory, lru, out + OFF_MEM);
  }
}